// Round 14
// baseline (374.127 us; speedup 1.0000x reference)
//
#include <hip/hip_runtime.h>
#include <math.h>

#define NN 131071
#define HD 128
#define N_INTERNAL 65535
#define LEAF_BASE 65535

typedef short bf16x8 __attribute__((ext_vector_type(8)));
typedef unsigned short u16x8 __attribute__((ext_vector_type(8)));
typedef unsigned short u16x4 __attribute__((ext_vector_type(4)));
typedef float f32x4 __attribute__((ext_vector_type(4)));

__device__ __forceinline__ float sigm(float z) { return 1.0f / (1.0f + __expf(-z)); }
__device__ __forceinline__ float tanh_f(float z) { return 1.0f - 2.0f / (__expf(2.0f * z) + 1.0f); }

__device__ __forceinline__ unsigned short f2bf(float f) {
    unsigned u = __float_as_uint(f);
    u += 0x7FFFu + ((u >> 16) & 1u);
    return (unsigned short)(u >> 16);
}
__device__ __forceinline__ float bf2f(unsigned short b) {
    return __uint_as_float(((unsigned)b) << 16);
}

__device__ __forceinline__ f32x4 mfma16(bf16x8 a, bf16x8 b, f32x4 c) {
    return __builtin_amdgcn_mfma_f32_16x16x32_bf16(a, b, c, 0, 0, 0);
}

__device__ __forceinline__ bf16x8 pk8(float4 a, float4 b) {
    u16x8 p;
    p[0] = f2bf(a.x); p[1] = f2bf(a.y); p[2] = f2bf(a.z); p[3] = f2bf(a.w);
    p[4] = f2bf(b.x); p[5] = f2bf(b.y); p[6] = f2bf(b.z); p[7] = f2bf(b.w);
    return *(bf16x8*)&p;
}

// A-fragment from LDS, rows consumed contiguously (tail3): key (row&7)
__device__ __forceinline__ bf16x8 lds_frag(const unsigned short* region, int row, int ks, int kl) {
    int cc = ks * 4 + kl;
    return *(const bf16x8*)&region[row * HD + ((cc ^ (row & 7)) << 3)];
}

// A-fragment from LDS, rows consumed at stride 2: key ((row>>1)&7)
__device__ __forceinline__ bf16x8 lds_frag2(const unsigned short* region, int row, int ks, int kl) {
    int cc = ks * 4 + kl;
    return *(const bf16x8*)&region[row * HD + ((cc ^ ((row >> 1) & 7)) << 3)];
}

// B-fragment from fragment-order-packed weights
__device__ __forceinline__ bf16x8 frag2(const unsigned short* M, int ct, int ks, int lane) {
    return *(const bf16x8*)&M[(((ct * 4 + ks) * 64) + lane) * 8];
}

// 16B bf16 fragment from a row-major bf16 row pointer
__device__ __forceinline__ bf16x8 row_frag(const unsigned short* rowp, int ks, int kl) {
    return *(const bf16x8*)&rowp[ks * 32 + kl * 8];
}

// ---- prep: weights pack (64 blocks' worth) + emb f32->bf16 (3125 blocks' worth), one dispatch
__global__ __launch_bounds__(256) void prep_kernel(
    const float* __restrict__ W_iou, const float* __restrict__ U_iou,
    const float* __restrict__ W_f, const float* __restrict__ U_f,
    const float* __restrict__ emb,
    unsigned short* __restrict__ wpk, unsigned short* __restrict__ emb16)
{
    int bid = blockIdx.x;
    if (bid < 3125) {
        size_t idx = ((size_t)bid * 256 + threadIdx.x) * 8;
        float4 a = *(const float4*)(emb + idx);
        float4 b = *(const float4*)(emb + idx + 4);
        bf16x8 v = pk8(a, b);
        *(bf16x8*)&emb16[idx] = v;
    } else {
        int f = (bid - 3125) * 256 + threadIdx.x;   // 0..16383
        int mat = f >> 13;
        int rem = f & 8191;
        int ct = rem >> 8;
        int ks = (rem >> 6) & 3;
        int lane = rem & 63;
        int col = ct * 16 + (lane & 15);
        int k0 = ks * 32 + (lane >> 4) * 8;
        u16x8 out;
#pragma unroll
        for (int e = 0; e < 8; ++e) {
            int k = k0 + e;
            float v;
            if (mat == 0) v = (col < 384) ? W_iou[k * 384 + col] : W_f[k * HD + (col - 384)];
            else          v = (col < 384) ? U_iou[k * 384 + col] : U_f[k * HD + (col - 384)];
            out[e] = f2bf(v);
        }
        *(u16x8*)&wpk[(size_t)f * 8] = out;
    }
}

// ---- XP precompute + fused leaf gate math
__global__ __launch_bounds__(512) void xp_leaf2(
    const int* __restrict__ feat, const unsigned short* __restrict__ emb16,
    const unsigned short* __restrict__ WT2,
    const float* __restrict__ b_iou, const float* __restrict__ b_f,
    unsigned short* __restrict__ XPb, unsigned short* __restrict__ hb16,
    float* __restrict__ hbuf, float* __restrict__ cbuf)
{
    const int t = threadIdx.x;
    const int m0 = blockIdx.x * 64;
    const int lane = t & 63, w = t >> 6;
    const int jq = w & 3, mh = w >> 2;
    const int l15 = lane & 15, kl = lane >> 4;

    int na0 = m0 + (mh * 2 + 0) * 16 + l15;
    int na1 = m0 + (mh * 2 + 1) * 16 + l15;
    const unsigned short* x0p = emb16 + (size_t)feat[na0 < NN ? na0 : NN - 1] * HD;
    const unsigned short* x1p = emb16 + (size_t)feat[na1 < NN ? na1 : NN - 1] * HD;

    f32x4 zero = {0.f, 0.f, 0.f, 0.f};
    f32x4 acc[4][2][2];
#pragma unroll
    for (int g = 0; g < 4; ++g)
#pragma unroll
        for (int mp = 0; mp < 2; ++mp)
#pragma unroll
            for (int jt = 0; jt < 2; ++jt) acc[g][mp][jt] = zero;

#pragma unroll
    for (int ks = 0; ks < 4; ++ks) {
        bf16x8 a0 = row_frag(x0p, ks, kl);
        bf16x8 a1 = row_frag(x1p, ks, kl);
#pragma unroll
        for (int g = 0; g < 4; ++g) {
#pragma unroll
            for (int jt = 0; jt < 2; ++jt) {
                bf16x8 b = frag2(WT2, g * 8 + jq * 2 + jt, ks, lane);
                acc[g][0][jt] = mfma16(a0, b, acc[g][0][jt]);
                acc[g][1][jt] = mfma16(a1, b, acc[g][1][jt]);
            }
        }
    }

#pragma unroll
    for (int mp = 0; mp < 2; ++mp) {
#pragma unroll
        for (int jt = 0; jt < 2; ++jt) {
            int j = jq * 32 + jt * 16 + l15;
            int nb = m0 + (mh * 2 + mp) * 16 + kl * 4;
            float bi = b_iou[j], bo = b_iou[HD + j], bu = b_iou[2 * HD + j], bf = b_f[j];
#pragma unroll
            for (int r = 0; r < 4; ++r) {
                int n = nb + r;
                if (n >= NN) continue;
                if (n >= LEAF_BASE) {
                    float iv = sigm(acc[0][mp][jt][r] + bi);
                    float ov = sigm(acc[1][mp][jt][r] + bo);
                    float uv = tanh_f(acc[2][mp][jt][r] + bu);
                    float cv = iv * uv;
                    float hv = ov * tanh_f(cv);
                    cbuf[(size_t)n * HD + j] = cv;
                    hbuf[(size_t)n * HD + j] = hv;
                    hb16[(size_t)n * HD + j] = f2bf(hv);
                } else {
                    u16x4 pk;
                    pk[0] = f2bf(acc[0][mp][jt][r] + bi);
                    pk[1] = f2bf(acc[1][mp][jt][r] + bo);
                    pk[2] = f2bf(acc[2][mp][jt][r] + bu);
                    pk[3] = f2bf(acc[3][mp][jt][r] + bf);
                    *(u16x4*)&XPb[((size_t)n * HD + j) * 4] = pk;
                }
            }
        }
    }
}

// ---- pair kernel: computes TWO consecutive levels per dispatch.
__global__ __launch_bounds__(512) void pair_kernel(
    const unsigned short* __restrict__ UT2, const unsigned short* __restrict__ XPb,
    unsigned short* __restrict__ hb16,
    float* __restrict__ hbuf, float* __restrict__ cbuf, int base2)
{
    __shared__ unsigned short lds[256 * HD];   // 65536 B
    const int t = threadIdx.x;
    const int P0 = base2 + blockIdx.x * 64;    // first parent (global)
    const size_t g0 = 4 * (size_t)P0 + 3;      // first grandchild row (global)
    const int m0g = 2 * P0 + 1;                // first mid-level node (global)

    {   // stage 256 grandchild rows, coalesced 128B/thread
        int r = t >> 1, q = t & 1;
        const unsigned short* src = hb16 + (g0 + r) * HD + q * 64;
#pragma unroll
        for (int i = 0; i < 8; ++i) {
            bf16x8 v = *(const bf16x8*)(src + i * 8);
            int cc = q * 8 + i;
            *(bf16x8*)&lds[r * HD + ((cc ^ ((r >> 1) & 7)) << 3)] = v;
        }
    }
    __syncthreads();

    const int lane = t & 63, w = t >> 6;
    const int jq = w & 3, mh = w >> 2;
    const int l15 = lane & 15, kl = lane >> 4;
    f32x4 zero = {0.f, 0.f, 0.f, 0.f};

    // ---- pass A: 128 mid-level nodes in two half-passes; h kept in regs
    float hA[2][16];
#pragma unroll
    for (int half = 0; half < 2; ++half) {
        f32x4 acc[5][2][2];
#pragma unroll
        for (int g = 0; g < 5; ++g)
#pragma unroll
            for (int mp = 0; mp < 2; ++mp)
#pragma unroll
                for (int jt = 0; jt < 2; ++jt) acc[g][mp][jt] = zero;

#pragma unroll
        for (int ks = 0; ks < 4; ++ks) {
            bf16x8 ah1[2], ah2[2];
#pragma unroll
            for (int mp = 0; mp < 2; ++mp) {
                int i = half * 64 + mh * 32 + mp * 16 + l15;   // mid-level local row
                ah1[mp] = lds_frag2(lds, 2 * i + 0, ks, kl);
                ah2[mp] = lds_frag2(lds, 2 * i + 1, ks, kl);
            }
#pragma unroll
            for (int jt = 0; jt < 2; ++jt) {
                bf16x8 Bi = frag2(UT2,  0 + jq * 2 + jt, ks, lane);
                bf16x8 Bo = frag2(UT2,  8 + jq * 2 + jt, ks, lane);
                bf16x8 Bu = frag2(UT2, 16 + jq * 2 + jt, ks, lane);
                bf16x8 Bf = frag2(UT2, 24 + jq * 2 + jt, ks, lane);
#pragma unroll
                for (int mp = 0; mp < 2; ++mp) {
                    acc[0][mp][jt] = mfma16(ah1[mp], Bi, mfma16(ah2[mp], Bi, acc[0][mp][jt]));
                    acc[1][mp][jt] = mfma16(ah1[mp], Bo, mfma16(ah2[mp], Bo, acc[1][mp][jt]));
                    acc[2][mp][jt] = mfma16(ah1[mp], Bu, mfma16(ah2[mp], Bu, acc[2][mp][jt]));
                    acc[3][mp][jt] = mfma16(ah1[mp], Bf, acc[3][mp][jt]);
                    acc[4][mp][jt] = mfma16(ah2[mp], Bf, acc[4][mp][jt]);
                }
            }
        }

#pragma unroll
        for (int mp = 0; mp < 2; ++mp) {
#pragma unroll
            for (int jt = 0; jt < 2; ++jt) {
                int j = jq * 32 + jt * 16 + l15;
#pragma unroll
                for (int r = 0; r < 4; ++r) {
                    int i = half * 64 + mh * 32 + mp * 16 + kl * 4 + r;
                    int m = m0g + i;   // global mid-level node
                    u16x4 pk = *(const u16x4*)&XPb[((size_t)m * HD + j) * 4];
                    float iv = sigm(acc[0][mp][jt][r] + bf2f(pk[0]));
                    float ov = sigm(acc[1][mp][jt][r] + bf2f(pk[1]));
                    float uv = tanh_f(acc[2][mp][jt][r] + bf2f(pk[2]));
                    float fx = bf2f(pk[3]);
                    float f1 = sigm(acc[3][mp][jt][r] + fx);
                    float f2 = sigm(acc[4][mp][jt][r] + fx);
                    float c1 = cbuf[(size_t)(2 * m + 1) * HD + j];
                    float c2 = cbuf[(size_t)(2 * m + 2) * HD + j];
                    float cn = fmaf(iv, uv, fmaf(f1, c1, f2 * c2));
                    float hn = ov * tanh_f(cn);
                    cbuf[(size_t)m * HD + j] = cn;
                    hbuf[(size_t)m * HD + j] = hn;
                    hA[half][mp * 8 + jt * 4 + r] = hn;
                }
            }
        }
    }
    __syncthreads();   // all LDS grandchild reads complete

    // handoff: mid-level h (bf16) -> LDS rows 0..127, stride-2 swizzle key
    {
#pragma unroll
        for (int half = 0; half < 2; ++half)
#pragma unroll
            for (int mp = 0; mp < 2; ++mp)
#pragma unroll
                for (int jt = 0; jt < 2; ++jt) {
                    int j = jq * 32 + jt * 16 + l15;
                    int cc = j >> 3;
#pragma unroll
                    for (int r = 0; r < 4; ++r) {
                        int i = half * 64 + mh * 32 + mp * 16 + kl * 4 + r;
                        lds[i * HD + ((cc ^ ((i >> 1) & 7)) << 3) + (j & 7)] =
                            f2bf(hA[half][mp * 8 + jt * 4 + r]);
                    }
                }
    }
    __syncthreads();

    // ---- pass B: 64 parents from LDS mid-level h
    {
        f32x4 acc[5][2][2];
#pragma unroll
        for (int g = 0; g < 5; ++g)
#pragma unroll
            for (int mp = 0; mp < 2; ++mp)
#pragma unroll
                for (int jt = 0; jt < 2; ++jt) acc[g][mp][jt] = zero;

#pragma unroll
        for (int ks = 0; ks < 4; ++ks) {
            bf16x8 ah1[2], ah2[2];
#pragma unroll
            for (int mp = 0; mp < 2; ++mp) {
                int p = mh * 32 + mp * 16 + l15;   // parent local row
                ah1[mp] = lds_frag2(lds, 2 * p + 0, ks, kl);
                ah2[mp] = lds_frag2(lds, 2 * p + 1, ks, kl);
            }
#pragma unroll
            for (int jt = 0; jt < 2; ++jt) {
                bf16x8 Bi = frag2(UT2,  0 + jq * 2 + jt, ks, lane);
                bf16x8 Bo = frag2(UT2,  8 + jq * 2 + jt, ks, lane);
                bf16x8 Bu = frag2(UT2, 16 + jq * 2 + jt, ks, lane);
                bf16x8 Bf = frag2(UT2, 24 + jq * 2 + jt, ks, lane);
#pragma unroll
                for (int mp = 0; mp < 2; ++mp) {
                    acc[0][mp][jt] = mfma16(ah1[mp], Bi, mfma16(ah2[mp], Bi, acc[0][mp][jt]));
                    acc[1][mp][jt] = mfma16(ah1[mp], Bo, mfma16(ah2[mp], Bo, acc[1][mp][jt]));
                    acc[2][mp][jt] = mfma16(ah1[mp], Bu, mfma16(ah2[mp], Bu, acc[2][mp][jt]));
                    acc[3][mp][jt] = mfma16(ah1[mp], Bf, acc[3][mp][jt]);
                    acc[4][mp][jt] = mfma16(ah2[mp], Bf, acc[4][mp][jt]);
                }
            }
        }

#pragma unroll
        for (int mp = 0; mp < 2; ++mp) {
#pragma unroll
            for (int jt = 0; jt < 2; ++jt) {
                int j = jq * 32 + jt * 16 + l15;
#pragma unroll
                for (int r = 0; r < 4; ++r) {
                    int n = P0 + mh * 32 + mp * 16 + kl * 4 + r;
                    u16x4 pk = *(const u16x4*)&XPb[((size_t)n * HD + j) * 4];
                    float iv = sigm(acc[0][mp][jt][r] + bf2f(pk[0]));
                    float ov = sigm(acc[1][mp][jt][r] + bf2f(pk[1]));
                    float uv = tanh_f(acc[2][mp][jt][r] + bf2f(pk[2]));
                    float fx = bf2f(pk[3]);
                    float f1 = sigm(acc[3][mp][jt][r] + fx);
                    float f2 = sigm(acc[4][mp][jt][r] + fx);
                    float c1 = cbuf[(size_t)(2 * n + 1) * HD + j];
                    float c2 = cbuf[(size_t)(2 * n + 2) * HD + j];
                    float cn = fmaf(iv, uv, fmaf(f1, c1, f2 * c2));
                    float hn = ov * tanh_f(cn);
                    cbuf[(size_t)n * HD + j] = cn;
                    hbuf[(size_t)n * HD + j] = hn;
                    hb16[(size_t)n * HD + j] = f2bf(hn);
                }
            }
        }
    }
}

// ---- single level (used for level 9 only): children staged hb16->LDS
__global__ __launch_bounds__(512) void level_u3(
    const unsigned short* __restrict__ UT2, const unsigned short* __restrict__ XPb,
    const unsigned short* __restrict__ hb16_c, unsigned short* __restrict__ hb16,
    float* __restrict__ hbuf, float* __restrict__ cbuf, int base)
{
    __shared__ unsigned short chlds[128 * HD];
    const int t = threadIdx.x;
    const int m0 = blockIdx.x * 64;
    const size_t cr0 = 2 * (size_t)(base + m0) + 1;

    {
        int r = t >> 2, q = t & 3;
        const unsigned short* src = hb16_c + (cr0 + r) * HD + q * 32;
#pragma unroll
        for (int i = 0; i < 4; ++i) {
            bf16x8 v = *(const bf16x8*)(src + i * 8);
            int cc = q * 4 + i;
            *(bf16x8*)&chlds[r * HD + ((cc ^ ((r >> 1) & 7)) << 3)] = v;
        }
    }
    __syncthreads();

    const int lane = t & 63, w = t >> 6;
    const int jq = w & 3, mh = w >> 2;
    const int l15 = lane & 15, kl = lane >> 4;

    f32x4 zero = {0.f, 0.f, 0.f, 0.f};
    f32x4 acc[5][2][2];
#pragma unroll
    for (int g = 0; g < 5; ++g)
#pragma unroll
        for (int mp = 0; mp < 2; ++mp)
#pragma unroll
            for (int jt = 0; jt < 2; ++jt) acc[g][mp][jt] = zero;

#pragma unroll
    for (int ks = 0; ks < 4; ++ks) {
        bf16x8 ah1[2], ah2[2];
#pragma unroll
        for (int mp = 0; mp < 2; ++mp) {
            int pr = mh * 32 + mp * 16 + l15;
            ah1[mp] = lds_frag2(chlds, 2 * pr + 0, ks, kl);
            ah2[mp] = lds_frag2(chlds, 2 * pr + 1, ks, kl);
        }
#pragma unroll
        for (int jt = 0; jt < 2; ++jt) {
            bf16x8 Bi = frag2(UT2,  0 + jq * 2 + jt, ks, lane);
            bf16x8 Bo = frag2(UT2,  8 + jq * 2 + jt, ks, lane);
            bf16x8 Bu = frag2(UT2, 16 + jq * 2 + jt, ks, lane);
            bf16x8 Bf = frag2(UT2, 24 + jq * 2 + jt, ks, lane);
#pragma unroll
            for (int mp = 0; mp < 2; ++mp) {
                acc[0][mp][jt] = mfma16(ah1[mp], Bi, mfma16(ah2[mp], Bi, acc[0][mp][jt]));
                acc[1][mp][jt] = mfma16(ah1[mp], Bo, mfma16(ah2[mp], Bo, acc[1][mp][jt]));
                acc[2][mp][jt] = mfma16(ah1[mp], Bu, mfma16(ah2[mp], Bu, acc[2][mp][jt]));
                acc[3][mp][jt] = mfma16(ah1[mp], Bf, acc[3][mp][jt]);
                acc[4][mp][jt] = mfma16(ah2[mp], Bf, acc[4][mp][jt]);
            }
        }
    }

#pragma unroll
    for (int mp = 0; mp < 2; ++mp) {
#pragma unroll
        for (int jt = 0; jt < 2; ++jt) {
            int j = jq * 32 + jt * 16 + l15;
#pragma unroll
            for (int r = 0; r < 4; ++r) {
                int n = base + m0 + (mh * 2 + mp) * 16 + kl * 4 + r;
                u16x4 pk = *(const u16x4*)&XPb[((size_t)n * HD + j) * 4];
                float iv = sigm(acc[0][mp][jt][r] + bf2f(pk[0]));
                float ov = sigm(acc[1][mp][jt][r] + bf2f(pk[1]));
                float uv = tanh_f(acc[2][mp][jt][r] + bf2f(pk[2]));
                float fx = bf2f(pk[3]);
                float f1 = sigm(acc[3][mp][jt][r] + fx);
                float f2 = sigm(acc[4][mp][jt][r] + fx);
                float c1 = cbuf[(size_t)(2 * n + 1) * HD + j];
                float c2 = cbuf[(size_t)(2 * n + 2) * HD + j];
                float cn = fmaf(iv, uv, fmaf(f1, c1, f2 * c2));
                float hn = ov * tanh_f(cn);
                cbuf[(size_t)n * HD + j] = cn;
                hbuf[(size_t)n * HD + j] = hn;
                hb16[(size_t)n * HD + j] = f2bf(hn);
            }
        }
    }
}

// ---- fused tail v3 (unchanged): levels 10..16, ONE workgroup, h in LDS.
__global__ __launch_bounds__(512) void tail_kernel3(
    const unsigned short* __restrict__ UT2, const unsigned short* __restrict__ XPb,
    float* __restrict__ hbuf, float* __restrict__ cbuf)
{
    __shared__ unsigned short hlds[255 * HD];
    const int t = threadIdx.x;

    {
        int n = 127 + (t >> 2);
        int c0 = (t & 3) * 32;
        const float* src = hbuf + (size_t)n * HD + c0;
#pragma unroll
        for (int q = 0; q < 4; ++q) {
            float4 a = *(const float4*)(src + q * 8);
            float4 b = *(const float4*)(src + q * 8 + 4);
            int cc = (c0 >> 3) + q;
            bf16x8 v = pk8(a, b);
            *(bf16x8*)&hlds[n * HD + ((cc ^ (n & 7)) << 3)] = v;
        }
    }
    __syncthreads();

    const int lane = t & 63, w = t >> 6;
    const int jq = w & 3, mh = w >> 2;
    const int l15 = lane & 15, kl = lane >> 4;

#pragma unroll 1
    for (int lvl = 10; lvl <= 16; ++lvl) {
        const int count = 1 << (16 - lvl);
        const int base = count - 1;
        if (mh * 32 < count) {
            f32x4 zero = {0.f, 0.f, 0.f, 0.f};
            f32x4 acc[5][2][2];
#pragma unroll
            for (int g = 0; g < 5; ++g)
#pragma unroll
                for (int mp = 0; mp < 2; ++mp)
#pragma unroll
                    for (int jt = 0; jt < 2; ++jt) acc[g][mp][jt] = zero;

#pragma unroll
            for (int ks = 0; ks < 4; ++ks) {
                bf16x8 ah1[2], ah2[2];
#pragma unroll
                for (int mp = 0; mp < 2; ++mp) {
                    int row = mh * 32 + mp * 16 + l15;
                    int rr = row < count ? row : count - 1;
                    int n = base + rr;
                    ah1[mp] = lds_frag(hlds, 2 * n + 1, ks, kl);
                    ah2[mp] = lds_frag(hlds, 2 * n + 2, ks, kl);
                }
#pragma unroll
                for (int jt = 0; jt < 2; ++jt) {
                    bf16x8 Bi = frag2(UT2,  0 + jq * 2 + jt, ks, lane);
                    bf16x8 Bo = frag2(UT2,  8 + jq * 2 + jt, ks, lane);
                    bf16x8 Bu = frag2(UT2, 16 + jq * 2 + jt, ks, lane);
                    bf16x8 Bf = frag2(UT2, 24 + jq * 2 + jt, ks, lane);
#pragma unroll
                    for (int mp = 0; mp < 2; ++mp) {
                        acc[0][mp][jt] = mfma16(ah1[mp], Bi, mfma16(ah2[mp], Bi, acc[0][mp][jt]));
                        acc[1][mp][jt] = mfma16(ah1[mp], Bo, mfma16(ah2[mp], Bo, acc[1][mp][jt]));
                        acc[2][mp][jt] = mfma16(ah1[mp], Bu, mfma16(ah2[mp], Bu, acc[2][mp][jt]));
                        acc[3][mp][jt] = mfma16(ah1[mp], Bf, acc[3][mp][jt]);
                        acc[4][mp][jt] = mfma16(ah2[mp], Bf, acc[4][mp][jt]);
                    }
                }
            }

#pragma unroll
            for (int mp = 0; mp < 2; ++mp) {
#pragma unroll
                for (int jt = 0; jt < 2; ++jt) {
                    int j = jq * 32 + jt * 16 + l15;
#pragma unroll
                    for (int r = 0; r < 4; ++r) {
                        int row = mh * 32 + mp * 16 + kl * 4 + r;
                        if (row >= count) continue;
                        int n = base + row;
                        u16x4 pk = *(const u16x4*)&XPb[((size_t)n * HD + j) * 4];
                        float iv = sigm(acc[0][mp][jt][r] + bf2f(pk[0]));
                        float ov = sigm(acc[1][mp][jt][r] + bf2f(pk[1]));
                        float uv = tanh_f(acc[2][mp][jt][r] + bf2f(pk[2]));
                        float fx = bf2f(pk[3]);
                        float f1 = sigm(acc[3][mp][jt][r] + fx);
                        float f2 = sigm(acc[4][mp][jt][r] + fx);
                        float c1 = cbuf[(size_t)(2 * n + 1) * HD + j];
                        float c2 = cbuf[(size_t)(2 * n + 2) * HD + j];
                        float cn = fmaf(iv, uv, fmaf(f1, c1, f2 * c2));
                        float hn = ov * tanh_f(cn);
                        cbuf[(size_t)n * HD + j] = cn;
                        hbuf[(size_t)n * HD + j] = hn;
                        int cc = j >> 3;
                        hlds[n * HD + ((cc ^ (n & 7)) << 3) + (j & 7)] = f2bf(hn);
                    }
                }
            }
        }
        __syncthreads();
    }
}

// ---------------- scalar fallback (known-correct R3 path) ----------------
template <int MT>
__global__ __launch_bounds__(128) void leaf_kernel(
    const int* __restrict__ feat, const float* __restrict__ emb,
    const float* __restrict__ W_iou, const float* __restrict__ b_iou,
    float* __restrict__ hbuf, float* __restrict__ cbuf, int base)
{
    __shared__ float X[MT][HD];
    const int j = threadIdx.x;
    const int m0 = blockIdx.x * MT;
#pragma unroll
    for (int m = 0; m < MT; ++m) {
        int n = base + m0 + m;
        X[m][j] = emb[(size_t)feat[n] * HD + j];
    }
    __syncthreads();
    float ai[MT], ao[MT], au[MT];
#pragma unroll
    for (int m = 0; m < MT; ++m) {
        ai[m] = b_iou[j]; ao[m] = b_iou[HD + j]; au[m] = b_iou[2 * HD + j];
    }
#pragma unroll 4
    for (int k = 0; k < HD; ++k) {
        float wi = W_iou[k * 3 * HD + j];
        float wo = W_iou[k * 3 * HD + HD + j];
        float wu = W_iou[k * 3 * HD + 2 * HD + j];
#pragma unroll
        for (int m = 0; m < MT; ++m) {
            float x = X[m][k];
            ai[m] = fmaf(x, wi, ai[m]); ao[m] = fmaf(x, wo, ao[m]); au[m] = fmaf(x, wu, au[m]);
        }
    }
#pragma unroll
    for (int m = 0; m < MT; ++m) {
        int n = base + m0 + m;
        float iv = sigm(ai[m]); float ov = sigm(ao[m]); float uv = tanh_f(au[m]);
        float cv = iv * uv;
        cbuf[(size_t)n * HD + j] = cv;
        hbuf[(size_t)n * HD + j] = ov * tanh_f(cv);
    }
}

template <int MT>
__global__ __launch_bounds__(128) void level_kernel(
    const int* __restrict__ feat, const float* __restrict__ emb,
    const float* __restrict__ W_iou, const float* __restrict__ b_iou,
    const float* __restrict__ U_iou,
    const float* __restrict__ W_f, const float* __restrict__ b_f,
    const float* __restrict__ U_f,
    float* __restrict__ hbuf, float* __restrict__ cbuf, int base)
{
    __shared__ float X[MT][HD];
    __shared__ float H1[MT][HD];
    __shared__ float H2[MT][HD];
    const int j = threadIdx.x;
    const int m0 = blockIdx.x * MT;
#pragma unroll
    for (int m = 0; m < MT; ++m) {
        int n = base + m0 + m;
        X[m][j]  = emb[(size_t)feat[n] * HD + j];
        H1[m][j] = hbuf[(size_t)(2 * n + 1) * HD + j];
        H2[m][j] = hbuf[(size_t)(2 * n + 2) * HD + j];
    }
    __syncthreads();
    float ai[MT], ao[MT], au[MT], g1[MT], g2[MT];
#pragma unroll
    for (int m = 0; m < MT; ++m) {
        ai[m] = b_iou[j]; ao[m] = b_iou[HD + j]; au[m] = b_iou[2 * HD + j];
        g1[m] = b_f[j]; g2[m] = b_f[j];
    }
#pragma unroll 2
    for (int k = 0; k < HD; ++k) {
        float wi = W_iou[k * 3 * HD + j];
        float wo = W_iou[k * 3 * HD + HD + j];
        float wu = W_iou[k * 3 * HD + 2 * HD + j];
        float ui = U_iou[k * 3 * HD + j];
        float uo = U_iou[k * 3 * HD + HD + j];
        float uu = U_iou[k * 3 * HD + 2 * HD + j];
        float wf = W_f[k * HD + j];
        float uf = U_f[k * HD + j];
#pragma unroll
        for (int m = 0; m < MT; ++m) {
            float x = X[m][k]; float h1 = H1[m][k]; float h2 = H2[m][k]; float hs = h1 + h2;
            ai[m] = fmaf(x, wi, fmaf(hs, ui, ai[m]));
            ao[m] = fmaf(x, wo, fmaf(hs, uo, ao[m]));
            au[m] = fmaf(x, wu, fmaf(hs, uu, au[m]));
            g1[m] = fmaf(x, wf, fmaf(h1, uf, g1[m]));
            g2[m] = fmaf(x, wf, fmaf(h2, uf, g2[m]));
        }
    }
#pragma unroll
    for (int m = 0; m < MT; ++m) {
        int n = base + m0 + m;
        float iv = sigm(ai[m]); float ov = sigm(ao[m]); float uv = tanh_f(au[m]);
        float f1 = sigm(g1[m]); float f2 = sigm(g2[m]);
        float c1 = cbuf[(size_t)(2 * n + 1) * HD + j];
        float c2 = cbuf[(size_t)(2 * n + 2) * HD + j];
        float cn = fmaf(iv, uv, fmaf(f1, c1, f2 * c2));
        cbuf[(size_t)n * HD + j] = cn;
        hbuf[(size_t)n * HD + j] = ov * tanh_f(cn);
    }
}

extern "C" void kernel_launch(void* const* d_in, const int* in_sizes, int n_in,
                              void* d_out, int out_size, void* d_ws, size_t ws_size,
                              hipStream_t stream)
{
    const int*   feat  = (const int*)d_in[0];
    const float* emb   = (const float*)d_in[4];
    const float* W_iou = (const float*)d_in[5];
    const float* b_iou = (const float*)d_in[6];
    const float* U_iou = (const float*)d_in[7];
    const float* W_f   = (const float*)d_in[8];
    const float* b_f   = (const float*)d_in[9];
    const float* U_f   = (const float*)d_in[10];

    float* hbuf = (float*)d_out;
    float* cbuf = hbuf + (size_t)NN * HD;

    const size_t PACK_BYTES = 2u * 65536u * 2u;                      // 256 KB
    const size_t XP_BYTES   = (size_t)N_INTERNAL * HD * 4 * 2;       // ~67 MB
    const size_t HB_BYTES   = (size_t)131072 * HD * 2;               // 33.5 MB
    const size_t EMB_BYTES  = (size_t)50000 * HD * 2;                // 12.8 MB
    if (ws_size >= PACK_BYTES + XP_BYTES + HB_BYTES + EMB_BYTES) {
        unsigned short* wpk = (unsigned short*)d_ws;
        const unsigned short* WT2 = wpk;
        const unsigned short* UT2 = wpk + 65536;
        unsigned short* XPb  = (unsigned short*)((char*)d_ws + PACK_BYTES);
        unsigned short* hb16 = (unsigned short*)((char*)d_ws + PACK_BYTES + XP_BYTES);
        unsigned short* emb16= (unsigned short*)((char*)d_ws + PACK_BYTES + XP_BYTES + HB_BYTES);

        prep_kernel<<<3189, 256, 0, stream>>>(W_iou, U_iou, W_f, U_f, emb, wpk, emb16);
        xp_leaf2<<<2048, 512, 0, stream>>>(feat, emb16, WT2, b_iou, b_f, XPb, hb16, hbuf, cbuf);

        // pairs (1,2),(3,4),(5,6),(7,8): base2 = parent-level base, grid = count2/64
        pair_kernel<<<256, 512, 0, stream>>>(UT2, XPb, hb16, hbuf, cbuf, 16383);
        pair_kernel<<<64, 512, 0, stream>>>(UT2, XPb, hb16, hbuf, cbuf, 4095);
        pair_kernel<<<16, 512, 0, stream>>>(UT2, XPb, hb16, hbuf, cbuf, 1023);
        pair_kernel<<<4, 512, 0, stream>>>(UT2, XPb, hb16, hbuf, cbuf, 255);

        level_u3<<<2, 512, 0, stream>>>(UT2, XPb, hb16, hb16, hbuf, cbuf, 127);
        tail_kernel3<<<1, 512, 0, stream>>>(UT2, XPb, hbuf, cbuf);
    } else {
        // fallback: scalar path (correct, slower)
        leaf_kernel<16><<<65536 / 16, 128, 0, stream>>>(feat, emb, W_iou, b_iou, hbuf, cbuf, 65535);
        for (int lvl = 1; lvl <= 16; ++lvl) {
            const int d = 16 - lvl;
            const int count = 1 << d;
            const int base = count - 1;
            if (count >= 16) {
                level_kernel<16><<<count / 16, 128, 0, stream>>>(
                    feat, emb, W_iou, b_iou, U_iou, W_f, b_f, U_f, hbuf, cbuf, base);
            } else if (count == 8) {
                level_kernel<8><<<1, 128, 0, stream>>>(
                    feat, emb, W_iou, b_iou, U_iou, W_f, b_f, U_f, hbuf, cbuf, base);
            } else if (count == 4) {
                level_kernel<4><<<1, 128, 0, stream>>>(
                    feat, emb, W_iou, b_iou, U_iou, W_f, b_f, U_f, hbuf, cbuf, base);
            } else if (count == 2) {
                level_kernel<2><<<1, 128, 0, stream>>>(
                    feat, emb, W_iou, b_iou, U_iou, W_f, b_f, U_f, hbuf, cbuf, base);
            } else {
                level_kernel<1><<<1, 128, 0, stream>>>(
                    feat, emb, W_iou, b_iou, U_iou, W_f, b_f, U_f, hbuf, cbuf, base);
            }
        }
    }
}

// Round 16
// 291.172 us; speedup vs baseline: 1.2849x; 1.2849x over previous
//
#include <hip/hip_runtime.h>
#include <math.h>

#define NN 131071
#define HD 128
#define N_INTERNAL 65535
#define LEAF_BASE 65535

typedef short bf16x8 __attribute__((ext_vector_type(8)));
typedef unsigned short u16x8 __attribute__((ext_vector_type(8)));
typedef unsigned short u16x4 __attribute__((ext_vector_type(4)));
typedef float f32x4 __attribute__((ext_vector_type(4)));

__device__ __forceinline__ float sigm(float z) { return 1.0f / (1.0f + __expf(-z)); }
__device__ __forceinline__ float tanh_f(float z) { return 1.0f - 2.0f / (__expf(2.0f * z) + 1.0f); }

__device__ __forceinline__ unsigned short f2bf(float f) {
    unsigned u = __float_as_uint(f);
    u += 0x7FFFu + ((u >> 16) & 1u);
    return (unsigned short)(u >> 16);
}
__device__ __forceinline__ float bf2f(unsigned short b) {
    return __uint_as_float(((unsigned)b) << 16);
}

__device__ __forceinline__ f32x4 mfma16(bf16x8 a, bf16x8 b, f32x4 c) {
    return __builtin_amdgcn_mfma_f32_16x16x32_bf16(a, b, c, 0, 0, 0);
}

__device__ __forceinline__ float4 addf4(float4 a, float4 b) {
    float4 r; r.x = a.x + b.x; r.y = a.y + b.y; r.z = a.z + b.z; r.w = a.w + b.w; return r;
}

__device__ __forceinline__ bf16x8 pk8(float4 a, float4 b) {
    u16x8 p;
    p[0] = f2bf(a.x); p[1] = f2bf(a.y); p[2] = f2bf(a.z); p[3] = f2bf(a.w);
    p[4] = f2bf(b.x); p[5] = f2bf(b.y); p[6] = f2bf(b.z); p[7] = f2bf(b.w);
    return *(bf16x8*)&p;
}

// store 8 f32 (two float4) as bf16 chunk cc (16B) of row r, XOR-swizzled (key r&7)
__device__ __forceinline__ void lds_store8(unsigned short* region, int r, int cc, float4 a, float4 b) {
    u16x8 p;
    p[0] = f2bf(a.x); p[1] = f2bf(a.y); p[2] = f2bf(a.z); p[3] = f2bf(a.w);
    p[4] = f2bf(b.x); p[5] = f2bf(b.y); p[6] = f2bf(b.z); p[7] = f2bf(b.w);
    *(u16x8*)&region[r * HD + ((cc ^ (r & 7)) << 3)] = p;
}

// A-fragment from LDS, key (row&7)
__device__ __forceinline__ bf16x8 lds_frag(const unsigned short* region, int row, int ks, int kl) {
    int cc = ks * 4 + kl;
    return *(const bf16x8*)&region[row * HD + ((cc ^ (row & 7)) << 3)];
}

// B-fragment from fragment-order-packed weights
__device__ __forceinline__ bf16x8 frag2(const unsigned short* M, int ct, int ks, int lane) {
    return *(const bf16x8*)&M[(((ct * 4 + ks) * 64) + lane) * 8];
}

// 16B bf16 fragment from a row-major bf16 row pointer
__device__ __forceinline__ bf16x8 row_frag(const unsigned short* rowp, int ks, int kl) {
    return *(const bf16x8*)&rowp[ks * 32 + kl * 8];
}

// ---- prep: weights pack + emb f32->bf16, one dispatch
__global__ __launch_bounds__(256) void prep_kernel(
    const float* __restrict__ W_iou, const float* __restrict__ U_iou,
    const float* __restrict__ W_f, const float* __restrict__ U_f,
    const float* __restrict__ emb,
    unsigned short* __restrict__ wpk, unsigned short* __restrict__ emb16)
{
    int bid = blockIdx.x;
    if (bid < 3125) {
        size_t idx = ((size_t)bid * 256 + threadIdx.x) * 8;
        float4 a = *(const float4*)(emb + idx);
        float4 b = *(const float4*)(emb + idx + 4);
        bf16x8 v = pk8(a, b);
        *(bf16x8*)&emb16[idx] = v;
    } else {
        int f = (bid - 3125) * 256 + threadIdx.x;   // 0..16383
        int mat = f >> 13;
        int rem = f & 8191;
        int ct = rem >> 8;
        int ks = (rem >> 6) & 3;
        int lane = rem & 63;
        int col = ct * 16 + (lane & 15);
        int k0 = ks * 32 + (lane >> 4) * 8;
        u16x8 out;
#pragma unroll
        for (int e = 0; e < 8; ++e) {
            int k = k0 + e;
            float v;
            if (mat == 0) v = (col < 384) ? W_iou[k * 384 + col] : W_f[k * HD + (col - 384)];
            else          v = (col < 384) ? U_iou[k * 384 + col] : U_f[k * HD + (col - 384)];
            out[e] = f2bf(v);
        }
        *(u16x8*)&wpk[(size_t)f * 8] = out;
    }
}

// ---- XP precompute + fused leaf gate math (emb16 direct gather; no hb16)
__global__ __launch_bounds__(512) void xp_leaf2(
    const int* __restrict__ feat, const unsigned short* __restrict__ emb16,
    const unsigned short* __restrict__ WT2,
    const float* __restrict__ b_iou, const float* __restrict__ b_f,
    unsigned short* __restrict__ XPb,
    float* __restrict__ hbuf, float* __restrict__ cbuf)
{
    const int t = threadIdx.x;
    const int m0 = blockIdx.x * 64;
    const int lane = t & 63, w = t >> 6;
    const int jq = w & 3, mh = w >> 2;
    const int l15 = lane & 15, kl = lane >> 4;

    int na0 = m0 + (mh * 2 + 0) * 16 + l15;
    int na1 = m0 + (mh * 2 + 1) * 16 + l15;
    const unsigned short* x0p = emb16 + (size_t)feat[na0 < NN ? na0 : NN - 1] * HD;
    const unsigned short* x1p = emb16 + (size_t)feat[na1 < NN ? na1 : NN - 1] * HD;

    f32x4 zero = {0.f, 0.f, 0.f, 0.f};
    f32x4 acc[4][2][2];
#pragma unroll
    for (int g = 0; g < 4; ++g)
#pragma unroll
        for (int mp = 0; mp < 2; ++mp)
#pragma unroll
            for (int jt = 0; jt < 2; ++jt) acc[g][mp][jt] = zero;

#pragma unroll
    for (int ks = 0; ks < 4; ++ks) {
        bf16x8 a0 = row_frag(x0p, ks, kl);
        bf16x8 a1 = row_frag(x1p, ks, kl);
#pragma unroll
        for (int g = 0; g < 4; ++g) {
#pragma unroll
            for (int jt = 0; jt < 2; ++jt) {
                bf16x8 b = frag2(WT2, g * 8 + jq * 2 + jt, ks, lane);
                acc[g][0][jt] = mfma16(a0, b, acc[g][0][jt]);
                acc[g][1][jt] = mfma16(a1, b, acc[g][1][jt]);
            }
        }
    }

#pragma unroll
    for (int mp = 0; mp < 2; ++mp) {
#pragma unroll
        for (int jt = 0; jt < 2; ++jt) {
            int j = jq * 32 + jt * 16 + l15;
            int nb = m0 + (mh * 2 + mp) * 16 + kl * 4;
            float bi = b_iou[j], bo = b_iou[HD + j], bu = b_iou[2 * HD + j], bf = b_f[j];
#pragma unroll
            for (int r = 0; r < 4; ++r) {
                int n = nb + r;
                if (n >= NN) continue;
                if (n >= LEAF_BASE) {
                    float iv = sigm(acc[0][mp][jt][r] + bi);
                    float ov = sigm(acc[1][mp][jt][r] + bo);
                    float uv = tanh_f(acc[2][mp][jt][r] + bu);
                    float cv = iv * uv;
                    float hv = ov * tanh_f(cv);
                    cbuf[(size_t)n * HD + j] = cv;
                    hbuf[(size_t)n * HD + j] = hv;
                } else {
                    u16x4 pk;
                    pk[0] = f2bf(acc[0][mp][jt][r] + bi);
                    pk[1] = f2bf(acc[1][mp][jt][r] + bo);
                    pk[2] = f2bf(acc[2][mp][jt][r] + bu);
                    pk[3] = f2bf(acc[3][mp][jt][r] + bf);
                    *(u16x4*)&XPb[((size_t)n * HD + j) * 4] = pk;
                }
            }
        }
    }
}

// ---- internal level body (R9-verified): f32 children staged to LDS bf16. 64 nodes/pass.
__device__ __forceinline__ void level_body(
    unsigned short* lds,
    const unsigned short* __restrict__ UT2, const unsigned short* __restrict__ XPb,
    float* __restrict__ hbuf, float* __restrict__ cbuf, int base, int count, int m0)
{
    unsigned short* ldshs = lds;
    unsigned short* ldsh1 = lds + 8192;
    unsigned short* ldsh2 = lds + 16384;

    const int t = threadIdx.x;
    {
        int r = t >> 3, c8 = t & 7;
        int row = m0 + r;
        int n = base + (row < count ? row : 0);
        const float* s1 = hbuf + (size_t)(2 * n + 1) * HD + c8 * 16;
        const float* s2 = hbuf + (size_t)(2 * n + 2) * HD + c8 * 16;
        float4 p0 = *(const float4*)(s1 + 0);
        float4 p1 = *(const float4*)(s1 + 4);
        float4 p2 = *(const float4*)(s1 + 8);
        float4 p3 = *(const float4*)(s1 + 12);
        float4 q0 = *(const float4*)(s2 + 0);
        float4 q1 = *(const float4*)(s2 + 4);
        float4 q2 = *(const float4*)(s2 + 8);
        float4 q3 = *(const float4*)(s2 + 12);
        lds_store8(ldsh1, r, c8 * 2 + 0, p0, p1);
        lds_store8(ldsh1, r, c8 * 2 + 1, p2, p3);
        lds_store8(ldsh2, r, c8 * 2 + 0, q0, q1);
        lds_store8(ldsh2, r, c8 * 2 + 1, q2, q3);
        lds_store8(ldshs, r, c8 * 2 + 0, addf4(p0, q0), addf4(p1, q1));
        lds_store8(ldshs, r, c8 * 2 + 1, addf4(p2, q2), addf4(p3, q3));
    }
    __syncthreads();

    const int lane = t & 63, w = t >> 6;
    const int jq = w & 3, mh = w >> 2;
    const int l15 = lane & 15, kl = lane >> 4;

    f32x4 zero = {0.f, 0.f, 0.f, 0.f};
    f32x4 acc[5][2][2];   // i,o,u,f1,f2
#pragma unroll
    for (int g = 0; g < 5; ++g)
#pragma unroll
        for (int mp = 0; mp < 2; ++mp)
#pragma unroll
            for (int jt = 0; jt < 2; ++jt) acc[g][mp][jt] = zero;

#pragma unroll
    for (int ks = 0; ks < 4; ++ks) {
        bf16x8 ahs0 = lds_frag(ldshs, (mh * 2 + 0) * 16 + l15, ks, kl);
        bf16x8 ahs1 = lds_frag(ldshs, (mh * 2 + 1) * 16 + l15, ks, kl);
        bf16x8 ah10 = lds_frag(ldsh1, (mh * 2 + 0) * 16 + l15, ks, kl);
        bf16x8 ah11 = lds_frag(ldsh1, (mh * 2 + 1) * 16 + l15, ks, kl);
        bf16x8 ah20 = lds_frag(ldsh2, (mh * 2 + 0) * 16 + l15, ks, kl);
        bf16x8 ah21 = lds_frag(ldsh2, (mh * 2 + 1) * 16 + l15, ks, kl);
#pragma unroll
        for (int jt = 0; jt < 2; ++jt) {
            bf16x8 Bi = frag2(UT2,  0 + jq * 2 + jt, ks, lane);
            bf16x8 Bo = frag2(UT2,  8 + jq * 2 + jt, ks, lane);
            bf16x8 Bu = frag2(UT2, 16 + jq * 2 + jt, ks, lane);
            bf16x8 Bf = frag2(UT2, 24 + jq * 2 + jt, ks, lane);
            acc[0][0][jt] = mfma16(ahs0, Bi, acc[0][0][jt]);
            acc[0][1][jt] = mfma16(ahs1, Bi, acc[0][1][jt]);
            acc[1][0][jt] = mfma16(ahs0, Bo, acc[1][0][jt]);
            acc[1][1][jt] = mfma16(ahs1, Bo, acc[1][1][jt]);
            acc[2][0][jt] = mfma16(ahs0, Bu, acc[2][0][jt]);
            acc[2][1][jt] = mfma16(ahs1, Bu, acc[2][1][jt]);
            acc[3][0][jt] = mfma16(ah10, Bf, acc[3][0][jt]);
            acc[3][1][jt] = mfma16(ah11, Bf, acc[3][1][jt]);
            acc[4][0][jt] = mfma16(ah20, Bf, acc[4][0][jt]);
            acc[4][1][jt] = mfma16(ah21, Bf, acc[4][1][jt]);
        }
    }

#pragma unroll
    for (int mp = 0; mp < 2; ++mp) {
#pragma unroll
        for (int jt = 0; jt < 2; ++jt) {
            int j = jq * 32 + jt * 16 + l15;
#pragma unroll
            for (int r = 0; r < 4; ++r) {
                int row = m0 + (mh * 2 + mp) * 16 + kl * 4 + r;
                if (row >= count) continue;
                int n = base + row;
                u16x4 pk = *(const u16x4*)&XPb[((size_t)n * HD + j) * 4];
                float iv = sigm(acc[0][mp][jt][r] + bf2f(pk[0]));
                float ov = sigm(acc[1][mp][jt][r] + bf2f(pk[1]));
                float uv = tanh_f(acc[2][mp][jt][r] + bf2f(pk[2]));
                float fx = bf2f(pk[3]);
                float f1 = sigm(acc[3][mp][jt][r] + fx);
                float f2 = sigm(acc[4][mp][jt][r] + fx);
                float c1 = cbuf[(size_t)(2 * n + 1) * HD + j];
                float c2 = cbuf[(size_t)(2 * n + 2) * HD + j];
                float cn = fmaf(iv, uv, fmaf(f1, c1, f2 * c2));
                cbuf[(size_t)n * HD + j] = cn;
                hbuf[(size_t)n * HD + j] = ov * tanh_f(cn);
            }
        }
    }
}

__global__ __launch_bounds__(512) void level_u_kernel(
    const unsigned short* __restrict__ UT2, const unsigned short* __restrict__ XPb,
    float* __restrict__ hbuf, float* __restrict__ cbuf, int base, int count)
{
    __shared__ unsigned short lds[3 * 64 * HD];
    level_body(lds, UT2, XPb, hbuf, cbuf, base, count, blockIdx.x * 64);
}

// ---- fused tail v3 (R9-verified): levels 10..16, ONE workgroup, h in LDS.
__global__ __launch_bounds__(512) void tail_kernel3(
    const unsigned short* __restrict__ UT2, const unsigned short* __restrict__ XPb,
    float* __restrict__ hbuf, float* __restrict__ cbuf)
{
    __shared__ unsigned short hlds[255 * HD];
    const int t = threadIdx.x;

    {
        int n = 127 + (t >> 2);
        int c0 = (t & 3) * 32;
        const float* src = hbuf + (size_t)n * HD + c0;
#pragma unroll
        for (int q = 0; q < 4; ++q) {
            float4 a = *(const float4*)(src + q * 8);
            float4 b = *(const float4*)(src + q * 8 + 4);
            int cc = (c0 >> 3) + q;
            bf16x8 v = pk8(a, b);
            *(bf16x8*)&hlds[n * HD + ((cc ^ (n & 7)) << 3)] = v;
        }
    }
    __syncthreads();

    const int lane = t & 63, w = t >> 6;
    const int jq = w & 3, mh = w >> 2;
    const int l15 = lane & 15, kl = lane >> 4;

#pragma unroll 1
    for (int lvl = 10; lvl <= 16; ++lvl) {
        const int count = 1 << (16 - lvl);
        const int base = count - 1;
        if (mh * 32 < count) {
            f32x4 zero = {0.f, 0.f, 0.f, 0.f};
            f32x4 acc[5][2][2];
#pragma unroll
            for (int g = 0; g < 5; ++g)
#pragma unroll
                for (int mp = 0; mp < 2; ++mp)
#pragma unroll
                    for (int jt = 0; jt < 2; ++jt) acc[g][mp][jt] = zero;

#pragma unroll
            for (int ks = 0; ks < 4; ++ks) {
                bf16x8 ah1[2], ah2[2];
#pragma unroll
                for (int mp = 0; mp < 2; ++mp) {
                    int row = mh * 32 + mp * 16 + l15;
                    int rr = row < count ? row : count - 1;
                    int n = base + rr;
                    ah1[mp] = lds_frag(hlds, 2 * n + 1, ks, kl);
                    ah2[mp] = lds_frag(hlds, 2 * n + 2, ks, kl);
                }
#pragma unroll
                for (int jt = 0; jt < 2; ++jt) {
                    bf16x8 Bi = frag2(UT2,  0 + jq * 2 + jt, ks, lane);
                    bf16x8 Bo = frag2(UT2,  8 + jq * 2 + jt, ks, lane);
                    bf16x8 Bu = frag2(UT2, 16 + jq * 2 + jt, ks, lane);
                    bf16x8 Bf = frag2(UT2, 24 + jq * 2 + jt, ks, lane);
#pragma unroll
                    for (int mp = 0; mp < 2; ++mp) {
                        acc[0][mp][jt] = mfma16(ah1[mp], Bi, mfma16(ah2[mp], Bi, acc[0][mp][jt]));
                        acc[1][mp][jt] = mfma16(ah1[mp], Bo, mfma16(ah2[mp], Bo, acc[1][mp][jt]));
                        acc[2][mp][jt] = mfma16(ah1[mp], Bu, mfma16(ah2[mp], Bu, acc[2][mp][jt]));
                        acc[3][mp][jt] = mfma16(ah1[mp], Bf, acc[3][mp][jt]);
                        acc[4][mp][jt] = mfma16(ah2[mp], Bf, acc[4][mp][jt]);
                    }
                }
            }

#pragma unroll
            for (int mp = 0; mp < 2; ++mp) {
#pragma unroll
                for (int jt = 0; jt < 2; ++jt) {
                    int j = jq * 32 + jt * 16 + l15;
#pragma unroll
                    for (int r = 0; r < 4; ++r) {
                        int row = mh * 32 + mp * 16 + kl * 4 + r;
                        if (row >= count) continue;
                        int n = base + row;
                        u16x4 pk = *(const u16x4*)&XPb[((size_t)n * HD + j) * 4];
                        float iv = sigm(acc[0][mp][jt][r] + bf2f(pk[0]));
                        float ov = sigm(acc[1][mp][jt][r] + bf2f(pk[1]));
                        float uv = tanh_f(acc[2][mp][jt][r] + bf2f(pk[2]));
                        float fx = bf2f(pk[3]);
                        float f1 = sigm(acc[3][mp][jt][r] + fx);
                        float f2 = sigm(acc[4][mp][jt][r] + fx);
                        float c1 = cbuf[(size_t)(2 * n + 1) * HD + j];
                        float c2 = cbuf[(size_t)(2 * n + 2) * HD + j];
                        float cn = fmaf(iv, uv, fmaf(f1, c1, f2 * c2));
                        float hn = ov * tanh_f(cn);
                        cbuf[(size_t)n * HD + j] = cn;
                        hbuf[(size_t)n * HD + j] = hn;
                        int cc = j >> 3;
                        hlds[n * HD + ((cc ^ (n & 7)) << 3) + (j & 7)] = f2bf(hn);
                    }
                }
            }
        }
        __syncthreads();
    }
}

// ---------------- scalar fallback (known-correct R3 path) ----------------
template <int MT>
__global__ __launch_bounds__(128) void leaf_kernel(
    const int* __restrict__ feat, const float* __restrict__ emb,
    const float* __restrict__ W_iou, const float* __restrict__ b_iou,
    float* __restrict__ hbuf, float* __restrict__ cbuf, int base)
{
    __shared__ float X[MT][HD];
    const int j = threadIdx.x;
    const int m0 = blockIdx.x * MT;
#pragma unroll
    for (int m = 0; m < MT; ++m) {
        int n = base + m0 + m;
        X[m][j] = emb[(size_t)feat[n] * HD + j];
    }
    __syncthreads();
    float ai[MT], ao[MT], au[MT];
#pragma unroll
    for (int m = 0; m < MT; ++m) {
        ai[m] = b_iou[j]; ao[m] = b_iou[HD + j]; au[m] = b_iou[2 * HD + j];
    }
#pragma unroll 4
    for (int k = 0; k < HD; ++k) {
        float wi = W_iou[k * 3 * HD + j];
        float wo = W_iou[k * 3 * HD + HD + j];
        float wu = W_iou[k * 3 * HD + 2 * HD + j];
#pragma unroll
        for (int m = 0; m < MT; ++m) {
            float x = X[m][k];
            ai[m] = fmaf(x, wi, ai[m]); ao[m] = fmaf(x, wo, ao[m]); au[m] = fmaf(x, wu, au[m]);
        }
    }
#pragma unroll
    for (int m = 0; m < MT; ++m) {
        int n = base + m0 + m;
        float iv = sigm(ai[m]); float ov = sigm(ao[m]); float uv = tanh_f(au[m]);
        float cv = iv * uv;
        cbuf[(size_t)n * HD + j] = cv;
        hbuf[(size_t)n * HD + j] = ov * tanh_f(cv);
    }
}

template <int MT>
__global__ __launch_bounds__(128) void level_kernel(
    const int* __restrict__ feat, const float* __restrict__ emb,
    const float* __restrict__ W_iou, const float* __restrict__ b_iou,
    const float* __restrict__ U_iou,
    const float* __restrict__ W_f, const float* __restrict__ b_f,
    const float* __restrict__ U_f,
    float* __restrict__ hbuf, float* __restrict__ cbuf, int base)
{
    __shared__ float X[MT][HD];
    __shared__ float H1[MT][HD];
    __shared__ float H2[MT][HD];
    const int j = threadIdx.x;
    const int m0 = blockIdx.x * MT;
#pragma unroll
    for (int m = 0; m < MT; ++m) {
        int n = base + m0 + m;
        X[m][j]  = emb[(size_t)feat[n] * HD + j];
        H1[m][j] = hbuf[(size_t)(2 * n + 1) * HD + j];
        H2[m][j] = hbuf[(size_t)(2 * n + 2) * HD + j];
    }
    __syncthreads();
    float ai[MT], ao[MT], au[MT], g1[MT], g2[MT];
#pragma unroll
    for (int m = 0; m < MT; ++m) {
        ai[m] = b_iou[j]; ao[m] = b_iou[HD + j]; au[m] = b_iou[2 * HD + j];
        g1[m] = b_f[j]; g2[m] = b_f[j];
    }
#pragma unroll 2
    for (int k = 0; k < HD; ++k) {
        float wi = W_iou[k * 3 * HD + j];
        float wo = W_iou[k * 3 * HD + HD + j];
        float wu = W_iou[k * 3 * HD + 2 * HD + j];
        float ui = U_iou[k * 3 * HD + j];
        float uo = U_iou[k * 3 * HD + HD + j];
        float uu = U_iou[k * 3 * HD + 2 * HD + j];
        float wf = W_f[k * HD + j];
        float uf = U_f[k * HD + j];
#pragma unroll
        for (int m = 0; m < MT; ++m) {
            float x = X[m][k]; float h1 = H1[m][k]; float h2 = H2[m][k]; float hs = h1 + h2;
            ai[m] = fmaf(x, wi, fmaf(hs, ui, ai[m]));
            ao[m] = fmaf(x, wo, fmaf(hs, uo, ao[m]));
            au[m] = fmaf(x, wu, fmaf(hs, uu, au[m]));
            g1[m] = fmaf(x, wf, fmaf(h1, uf, g1[m]));
            g2[m] = fmaf(x, wf, fmaf(h2, uf, g2[m]));
        }
    }
#pragma unroll
    for (int m = 0; m < MT; ++m) {
        int n = base + m0 + m;
        float iv = sigm(ai[m]); float ov = sigm(ao[m]); float uv = tanh_f(au[m]);
        float f1 = sigm(g1[m]); float f2 = sigm(g2[m]);
        float c1 = cbuf[(size_t)(2 * n + 1) * HD + j];
        float c2 = cbuf[(size_t)(2 * n + 2) * HD + j];
        float cn = fmaf(iv, uv, fmaf(f1, c1, f2 * c2));
        cbuf[(size_t)n * HD + j] = cn;
        hbuf[(size_t)n * HD + j] = ov * tanh_f(cn);
    }
}

extern "C" void kernel_launch(void* const* d_in, const int* in_sizes, int n_in,
                              void* d_out, int out_size, void* d_ws, size_t ws_size,
                              hipStream_t stream)
{
    const int*   feat  = (const int*)d_in[0];
    const float* emb   = (const float*)d_in[4];
    const float* W_iou = (const float*)d_in[5];
    const float* b_iou = (const float*)d_in[6];
    const float* U_iou = (const float*)d_in[7];
    const float* W_f   = (const float*)d_in[8];
    const float* b_f   = (const float*)d_in[9];
    const float* U_f   = (const float*)d_in[10];

    float* hbuf = (float*)d_out;
    float* cbuf = hbuf + (size_t)NN * HD;

    const size_t PACK_BYTES = 2u * 65536u * 2u;                      // 256 KB
    const size_t XP_BYTES   = (size_t)N_INTERNAL * HD * 4 * 2;       // ~67 MB
    const size_t EMB_BYTES  = (size_t)50000 * HD * 2;                // 12.8 MB
    if (ws_size >= PACK_BYTES + XP_BYTES + EMB_BYTES) {
        unsigned short* wpk = (unsigned short*)d_ws;
        const unsigned short* WT2 = wpk;
        const unsigned short* UT2 = wpk + 65536;
        unsigned short* XPb  = (unsigned short*)((char*)d_ws + PACK_BYTES);
        unsigned short* emb16= (unsigned short*)((char*)d_ws + PACK_BYTES + XP_BYTES);

        prep_kernel<<<3189, 256, 0, stream>>>(W_iou, U_iou, W_f, U_f, emb, wpk, emb16);
        xp_leaf2<<<2048, 512, 0, stream>>>(feat, emb16, WT2, b_iou, b_f, XPb, hbuf, cbuf);

        for (int lvl = 1; lvl <= 9; ++lvl) {
            const int count = 1 << (16 - lvl);
            const int base  = count - 1;
            level_u_kernel<<<count / 64, 512, 0, stream>>>(UT2, XPb, hbuf, cbuf, base, count);
        }
        tail_kernel3<<<1, 512, 0, stream>>>(UT2, XPb, hbuf, cbuf);
    } else {
        // fallback: scalar path (correct, slower)
        leaf_kernel<16><<<65536 / 16, 128, 0, stream>>>(feat, emb, W_iou, b_iou, hbuf, cbuf, 65535);
        for (int lvl = 1; lvl <= 16; ++lvl) {
            const int d = 16 - lvl;
            const int count = 1 << d;
            const int base = count - 1;
            if (count >= 16) {
                level_kernel<16><<<count / 16, 128, 0, stream>>>(
                    feat, emb, W_iou, b_iou, U_iou, W_f, b_f, U_f, hbuf, cbuf, base);
            } else if (count == 8) {
                level_kernel<8><<<1, 128, 0, stream>>>(
                    feat, emb, W_iou, b_iou, U_iou, W_f, b_f, U_f, hbuf, cbuf, base);
            } else if (count == 4) {
                level_kernel<4><<<1, 128, 0, stream>>>(
                    feat, emb, W_iou, b_iou, U_iou, W_f, b_f, U_f, hbuf, cbuf, base);
            } else if (count == 2) {
                level_kernel<2><<<1, 128, 0, stream>>>(
                    feat, emb, W_iou, b_iou, U_iou, W_f, b_f, U_f, hbuf, cbuf, base);
            } else {
                level_kernel<1><<<1, 128, 0, stream>>>(
                    feat, emb, W_iou, b_iou, U_iou, W_f, b_f, U_f, hbuf, cbuf, base);
            }
        }
    }
}